// Round 17
// baseline (113.016 us; speedup 1.0000x reference)
//
#include <hip/hip_runtime.h>

#define NB 256
#define NM 128
#define ND 64
#define NH 8

typedef float f32x4 __attribute__((ext_vector_type(4)));
typedef short bf16x8 __attribute__((ext_vector_type(8)));   // 8 bf16 = 4 VGPRs (16x16x32 A/B)
typedef short bf16x4 __attribute__((ext_vector_type(4)));   // 4 bf16 = 2 VGPRs (16x16x16 A/B)
typedef unsigned short ushort_t;

__device__ __forceinline__ ushort_t f2bf(float f) {   // RNE f32->bf16
    unsigned int x = __float_as_uint(f);
    x += 0x7fffu + ((x >> 16) & 1u);
    return (ushort_t)(x >> 16);
}
__device__ __forceinline__ unsigned pk2(float a, float b) {
    return (unsigned)f2bf(a) | ((unsigned)f2bf(b) << 16);
}
__device__ __forceinline__ bf16x4 pk4(float a, float b, float c, float d) {
    bf16x4 t;
    t[0] = (short)f2bf(a); t[1] = (short)f2bf(b);
    t[2] = (short)f2bf(c); t[3] = (short)f2bf(d);
    return t;
}

// XOR-swizzled LDS indices (T2), write and read via the SAME helper.
// sw64: 64-wide rows, 8 granule slots (16 rows -> 2-way alias; 2-way is free, m136).
// sw128: 128-wide rows, widened to row&15 -> 16 slots, full spread for the
// V^T tile whose rows span 0..63 (r16 counter showed 4.06M conflict cycles).
// XOR by multiples of 8 elems preserves 4-aligned b64 chunks.
__device__ __forceinline__ int sw64(int row, int col)  { return row * 64  + (col ^ ((row & 7) << 3)); }
__device__ __forceinline__ int sw128(int row, int col) { return row * 128 + (col ^ ((row & 15) << 3)); }

__device__ __forceinline__ f32x4 MFMA(bf16x8 a, bf16x8 b, f32x4 c) {
    return __builtin_amdgcn_mfma_f32_16x16x32_bf16(a, b, c, 0, 0, 0);
}

// 16x16x16 bf16 MFMA: A/B = 4 bf16/lane (lane(c,g): row/col=c, k=4g+j).
#if defined(__has_builtin)
#if __has_builtin(__builtin_amdgcn_mfma_f32_16x16x16bf16_1k)
#define HAVE_MFMA16 1
__device__ __forceinline__ f32x4 MFMA16(bf16x4 a, bf16x4 b, f32x4 c) {
    return __builtin_amdgcn_mfma_f32_16x16x16bf16_1k(a, b, c, 0, 0, 0);
}
#endif
#endif
#ifndef HAVE_MFMA16
__device__ __forceinline__ f32x4 MFMA16(bf16x4 a, bf16x4 b, f32x4 c) {
    f32x4 d;
    asm volatile("v_mfma_f32_16x16x16_bf16 %0, %1, %2, %3\n\ts_nop 7\n\ts_nop 7"
                 : "=v"(d) : "v"(a), "v"(b), "v"(c));
    return d;
}
#endif

// ---- prep: transpose weights to bf16 fragment layout in d_ws ----
// ws (ushort): WqT[512][64] @0, WkT @32768, WvT @65536, WpT[64][512] @98304 (256 KB)
extern "C" __global__ void geat_prep(const float* __restrict__ Wq,
                                     const float* __restrict__ Wk,
                                     const float* __restrict__ Wv,
                                     const float* __restrict__ Wp,
                                     ushort_t* __restrict__ ws)
{
    int idx = blockIdx.x * 256 + threadIdx.x;   // 0..131071
    int seg = idx >> 15;
    int r = idx & 32767;
    float v;
    if      (seg == 0) v = Wq[(r & 63) * 512 + (r >> 6)];    // WqT[o][d] = Wq[d][o]
    else if (seg == 1) v = Wk[(r & 63) * 512 + (r >> 6)];
    else if (seg == 2) v = Wv[(r & 63) * 512 + (r >> 6)];
    else               v = Wp[(r & 511) * 64 + (r >> 9)];    // WpT[c][k] = Wp[k][c]
    ws[idx] = f2bf(v);
}

// ============================================================================
// Producer/consumer fused kernel (r16 chassis, 103us) + three cuts:
//  (1) epack 8->4 regs (4-bit edge codes): frees regs at the pinned 84-reg
//      768-thread cap (65536/threads law) for in-flight LDS load buffering.
//  (2) sw128 XOR widened to row&15: V^T granule traffic fully bank-spread.
//  (3) T5 s_setprio(1) around the consumer MFMA region: producer/consumer
//      role-split is exactly the regime where setprio pays (m191).
// Grid 256 (1 block/CU), 768 thr = 12 waves = 3/SIMD guaranteed (r13: blocks
// never co-schedule; r12: 1024-thr -> 64-reg cap spills).
//  - waves 0..7  consumers: 16 rows each; per head: 4 b64 Q reads, fused
//    max-free S->exp->PV (r15: |s|<~6 so exp can't overflow; masked = exact 0;
//    normalize O~ once), oproj.
//  - waves 8..11 producers: K/V^T/Q of head h+1 (2 tiles of 16 rows).
// LDS 96 KB: 2 x {KB 8192, VTB 8192, QB 8192} ushorts. ONE barrier per head.
// DO NOT pass a >1 min-waves launch-bounds hint (r2/r5).
// ============================================================================
extern "C" __global__ __launch_bounds__(768, 1)
void geat_pc(const float* __restrict__ x, const int* __restrict__ edges,
             const float* __restrict__ bq, const float* __restrict__ bk,
             const float* __restrict__ bv, const float* __restrict__ ebias,
             const float* __restrict__ bp, const ushort_t* __restrict__ wt,
             float* __restrict__ out)
{
    __shared__ __align__(16) ushort_t sm[49152];  // 96 KB

    const int b    = blockIdx.x;
    const int tid  = threadIdx.x;
    const int w    = tid >> 6;          // wave 0..11
    const int lane = tid & 63;
    const int c    = lane & 15;
    const int g    = lane >> 4;
    const bool cons = (w < 8);
    const int mt   = cons ? (w * 16) : ((w - 8) * 32);   // consumer rows / producer base

    const ushort_t* WqT = wt;
    const ushort_t* WkT = wt + 32768;
    const ushort_t* WvT = wt + 65536;
    const ushort_t* WpT = wt + 98304;

    // ---- persistent per-role state ----
    unsigned epack[4];     // consumers: 32 edge codes x 4 bits (codes 0..4)
                           // code (nt, r) at epack[nt>>1] >> (16*(nt&1) + 4r)
    bf16x8   pxA[2][2];    // producers: x frags for rows mt+16*tile+c
    if (cons) {
        const int* erow = edges + (size_t)b * NM * NM + (mt + c) * NM;
#pragma unroll
        for (int p = 0; p < 4; ++p) {
            const int4 a0 = *(const int4*)&erow[(2 * p) * 16 + 4 * g];
            const int4 a1 = *(const int4*)&erow[(2 * p + 1) * 16 + 4 * g];
            epack[p] = (unsigned)(a0.x & 0xf)        | ((unsigned)(a0.y & 0xf) << 4)  |
                       ((unsigned)(a0.z & 0xf) << 8) | ((unsigned)(a0.w & 0xf) << 12) |
                       ((unsigned)(a1.x & 0xf) << 16)| ((unsigned)(a1.y & 0xf) << 20) |
                       ((unsigned)(a1.z & 0xf) << 24)| ((unsigned)(a1.w & 0xf) << 28);
        }
    } else {
#pragma unroll
        for (int tile = 0; tile < 2; ++tile) {
            const float* xb = x + (size_t)b * NM * ND + (mt + tile * 16 + c) * ND;
#pragma unroll
            for (int kt = 0; kt < 2; ++kt) {
                const float4 lo = *(const float4*)&xb[kt * 32 + 8 * g];
                const float4 hi = *(const float4*)&xb[kt * 32 + 8 * g + 4];
                bf16x8 f;
                f[0] = f2bf(lo.x); f[1] = f2bf(lo.y); f[2] = f2bf(lo.z); f[3] = f2bf(lo.w);
                f[4] = f2bf(hi.x); f[5] = f2bf(hi.y); f[6] = f2bf(hi.z); f[7] = f2bf(hi.w);
                pxA[tile][kt] = f;
            }
        }
    }

    f32x4 projacc[4];
#pragma unroll
    for (int i = 0; i < 4; ++i) projacc[i] = (f32x4)0.0f;

    // ---- producer: K + V^T + Q of head h2 into buf (32 rows: 2 tiles) ----
    auto PROJKVQ = [&](int h2, ushort_t* buf) {
        ushort_t* KBn = buf;
        ushort_t* VTn = buf + 8192;
        ushort_t* QBn = buf + 16384;
#pragma unroll
        for (int dt = 0; dt < 4; ++dt) {
            const int d0 = dt * 16;
            bf16x8 wqf[2], wkf[2], wvf[2];
#pragma unroll
            for (int kt = 0; kt < 2; ++kt) {
                const int woff = (h2 * 64 + d0 + c) * 64 + kt * 32 + 8 * g;
                wqf[kt] = *(const bf16x8*)&WqT[woff];
                wkf[kt] = *(const bf16x8*)&WkT[woff];
                wvf[kt] = *(const bf16x8*)&WvT[woff];
            }
            const float4 bqv = *(const float4*)&bq[h2 * 64 + d0 + 4 * g];
            const float4 bkv = *(const float4*)&bk[h2 * 64 + d0 + 4 * g];
            const float  bvv = bv[h2 * 64 + d0 + c];
#pragma unroll
            for (int tile = 0; tile < 2; ++tile) {
                f32x4 qT = (f32x4)0.0f, kT = (f32x4)0.0f, vn = (f32x4)0.0f;
#pragma unroll
                for (int kt = 0; kt < 2; ++kt) {
                    qT = MFMA(wqf[kt], pxA[tile][kt], qT);   // D: Q[row+c][d0+4g+r]
                    kT = MFMA(wkf[kt], pxA[tile][kt], kT);   // D: K[row+c][d0+4g+r]
                    vn = MFMA(pxA[tile][kt], wvf[kt], vn);   // D: V[row+4g+r][d0+c]
                }
                const int rowb = mt + tile * 16;
                uint2 qp, kp, vp;
                qp.x = pk2(qT[0] + bqv.x, qT[1] + bqv.y);
                qp.y = pk2(qT[2] + bqv.z, qT[3] + bqv.w);
                kp.x = pk2(kT[0] + bkv.x, kT[1] + bkv.y);
                kp.y = pk2(kT[2] + bkv.z, kT[3] + bkv.w);
                vp.x = pk2(vn[0] + bvv, vn[1] + bvv);
                vp.y = pk2(vn[2] + bvv, vn[3] + bvv);
                *(uint2*)&QBn[sw64(rowb + c, d0 + 4 * g)] = qp;
                *(uint2*)&KBn[sw64(rowb + c, d0 + 4 * g)] = kp;
                *(uint2*)&VTn[sw128(d0 + c, rowb + 4 * g)] = vp;
            }
        }
    };

    // ---- prologue: producers fill buffer 0 with head 0's K/V^T/Q ----
    if (!cons) PROJKVQ(0, sm);
    __syncthreads();

#pragma unroll 1
    for (int h = 0; h < NH; ++h) {
        ushort_t* bufc = sm + (h & 1) * 24576;
        ushort_t* bufn = sm + ((h & 1) ^ 1) * 24576;

        if (cons) {
            ushort_t* KBc = bufc;
            ushort_t* VTc = bufc + 8192;
            ushort_t* QBc = bufc + 16384;

            // ---- own-row Q granules straight from LDS ----
            bf16x4 qcur[4];
#pragma unroll
            for (int kt = 0; kt < 4; ++kt)
                qcur[kt] = *(const bf16x4*)&QBc[sw64(mt + c, kt * 16 + 4 * g)];

            const float eb0 = ebias[0 * NH + h], eb1 = ebias[1 * NH + h], eb2 = ebias[2 * NH + h];
            const float eb3 = ebias[3 * NH + h], eb4 = ebias[4 * NH + h];

            // ---- fused max-free S -> exp -> PV (T5: boost the MFMA-dense region) ----
            __builtin_amdgcn_s_setprio(1);
            f32x4 ot[4];
#pragma unroll
            for (int dt = 0; dt < 4; ++dt) ot[dt] = (f32x4)0.0f;
            float sum = 0.f;
#pragma unroll
            for (int nt = 0; nt < 8; ++nt) {
                const int n0 = nt * 16;
                f32x4 acc = (f32x4)0.0f;
#pragma unroll
                for (int kt = 0; kt < 4; ++kt) {
                    const bf16x4 kgr = *(const bf16x4*)&KBc[sw64(n0 + c, kt * 16 + 4 * g)];
                    acc = MFMA16(kgr, qcur[kt], acc);
                }
#pragma unroll
                for (int r = 0; r < 4; ++r) {
                    const int e = (epack[nt >> 1] >> ((nt & 1) * 16 + r * 4)) & 0xf;
                    const float bias = (e == 1) ? eb1 : (e == 2) ? eb2 : (e == 3) ? eb3 : (e == 4) ? eb4 : eb0;
                    float sv = acc[r] * 0.125f + bias;
                    sv = (sv > 0.f) ? sv : 0.2f * sv;          // leaky BEFORE mask (ref order)
                    acc[r] = (e > 0) ? __expf(sv) : 0.f;       // masked = exact 0, no exp
                }
                sum += (acc[0] + acc[1]) + (acc[2] + acc[3]);
                const bf16x4 pg = pk4(acc[0], acc[1], acc[2], acc[3]);   // unnormalized
#pragma unroll
                for (int dt = 0; dt < 4; ++dt) {
                    const bf16x4 vgr = *(const bf16x4*)&VTc[sw128(dt * 16 + c, n0 + 4 * g)];
                    ot[dt] = MFMA16(vgr, pg, ot[dt]);
                }
            }
            // row sum across the 4 lane-groups, then normalize O~ (16 muls)
            sum += __shfl_xor(sum, 16);
            sum += __shfl_xor(sum, 32);
            const float inv = 1.f / sum;

            // ---- out-proj accumulate from normalized O granules ----
            bf16x4 ogr[4];
#pragma unroll
            for (int dt = 0; dt < 4; ++dt)
                ogr[dt] = pk4(ot[dt][0] * inv, ot[dt][1] * inv, ot[dt][2] * inv, ot[dt][3] * inv);
#pragma unroll
            for (int nt4 = 0; nt4 < 4; ++nt4) {
                const int n0 = nt4 * 16;
#pragma unroll
                for (int dt = 0; dt < 4; ++dt) {
                    const bf16x4 wgr = *(const bf16x4*)&WpT[(n0 + c) * 512 + h * 64 + dt * 16 + 4 * g];
                    projacc[nt4] = MFMA16(ogr[dt], wgr, projacc[nt4]);
                }
            }
            __builtin_amdgcn_s_setprio(0);
        } else if (h < NH - 1) {
            // ---- producers: next head's K/V^T/Q into the other buffer ----
            PROJKVQ(h + 1, bufn);
        }

        __syncthreads();   // one barrier per head (uniform flow: outside the role ifs)
    }

    // ---- epilogue: consumers add bp and store ----
    if (cons) {
        float* og = out + (size_t)b * NM * ND;
#pragma unroll
        for (int nt4 = 0; nt4 < 4; ++nt4) {
            const int n0 = nt4 * 16;
            const float bpv = bp[n0 + c];
#pragma unroll
            for (int r = 0; r < 4; ++r)
                og[(mt + 4 * g + r) * ND + n0 + c] = projacc[nt4][r] + bpv;
        }
    }
}

extern "C" void kernel_launch(void* const* d_in, const int* in_sizes, int n_in,
                              void* d_out, int out_size, void* d_ws, size_t ws_size,
                              hipStream_t stream) {
    const float* x     = (const float*)d_in[0];
    const int*   edges = (const int*)d_in[1];
    const float* Wq    = (const float*)d_in[2];
    const float* bq    = (const float*)d_in[3];
    const float* Wk    = (const float*)d_in[4];
    const float* bk    = (const float*)d_in[5];
    const float* Wv    = (const float*)d_in[6];
    const float* bv    = (const float*)d_in[7];
    const float* eb    = (const float*)d_in[8];
    const float* Wp    = (const float*)d_in[9];
    const float* bp    = (const float*)d_in[10];
    float* out = (float*)d_out;
    ushort_t* ws = (ushort_t*)d_ws;   // needs 262144 B

    hipLaunchKernelGGL(geat_prep, dim3(512), dim3(256), 0, stream, Wq, Wk, Wv, Wp, ws);
    hipLaunchKernelGGL(geat_pc, dim3(NB), dim3(768), 0, stream,
                       x, edges, bq, bk, bv, eb, bp, ws, out);
}

// Round 18
// 100.930 us; speedup vs baseline: 1.1198x; 1.1198x over previous
//
#include <hip/hip_runtime.h>

#define NB 256
#define NM 128
#define ND 64
#define NH 8

typedef float f32x4 __attribute__((ext_vector_type(4)));
typedef short bf16x8 __attribute__((ext_vector_type(8)));   // 8 bf16 = 4 VGPRs (16x16x32 A/B)
typedef short bf16x4 __attribute__((ext_vector_type(4)));   // 4 bf16 = 2 VGPRs (16x16x16 A/B)
typedef unsigned short ushort_t;

__device__ __forceinline__ ushort_t f2bf(float f) {   // RNE f32->bf16
    unsigned int x = __float_as_uint(f);
    x += 0x7fffu + ((x >> 16) & 1u);
    return (ushort_t)(x >> 16);
}
__device__ __forceinline__ unsigned pk2(float a, float b) {
    return (unsigned)f2bf(a) | ((unsigned)f2bf(b) << 16);
}
__device__ __forceinline__ bf16x4 pk4(float a, float b, float c, float d) {
    bf16x4 t;
    t[0] = (short)f2bf(a); t[1] = (short)f2bf(b);
    t[2] = (short)f2bf(c); t[3] = (short)f2bf(d);
    return t;
}

// XOR-swizzled LDS indices (T2), write and read via the SAME helper (r16 form —
// r17's row&15 widening left SQ_LDS_BANK_CONFLICT bit-identical: reverted).
// XOR by multiples of 8 elems permutes 8-element blocks: b64 (4-elem) and b128
// (8-elem aligned) accesses both stay contiguous+aligned under it.
__device__ __forceinline__ int sw64(int row, int col)  { return row * 64  + (col ^ ((row & 7) << 3)); }
__device__ __forceinline__ int sw128(int row, int col) { return row * 128 + (col ^ ((row & 7) << 3)); }

__device__ __forceinline__ f32x4 MFMA(bf16x8 a, bf16x8 b, f32x4 c) {
    return __builtin_amdgcn_mfma_f32_16x16x32_bf16(a, b, c, 0, 0, 0);
}

// 16x16x16 bf16 MFMA: A/B = 4 bf16/lane (lane(c,g): row/col=c, k=4g+j).
#if defined(__has_builtin)
#if __has_builtin(__builtin_amdgcn_mfma_f32_16x16x16bf16_1k)
#define HAVE_MFMA16 1
__device__ __forceinline__ f32x4 MFMA16(bf16x4 a, bf16x4 b, f32x4 c) {
    return __builtin_amdgcn_mfma_f32_16x16x16bf16_1k(a, b, c, 0, 0, 0);
}
#endif
#endif
#ifndef HAVE_MFMA16
__device__ __forceinline__ f32x4 MFMA16(bf16x4 a, bf16x4 b, f32x4 c) {
    f32x4 d;
    asm volatile("v_mfma_f32_16x16x16_bf16 %0, %1, %2, %3\n\ts_nop 7\n\ts_nop 7"
                 : "=v"(d) : "v"(a), "v"(b), "v"(c));
    return d;
}
#endif

// ---- prep: transpose weights to bf16 fragment layout in d_ws ----
// ws (ushort): WqT[512][64] @0, WkT @32768, WvT @65536, WpT[64][512] @98304 (256 KB)
extern "C" __global__ void geat_prep(const float* __restrict__ Wq,
                                     const float* __restrict__ Wk,
                                     const float* __restrict__ Wv,
                                     const float* __restrict__ Wp,
                                     ushort_t* __restrict__ ws)
{
    int idx = blockIdx.x * 256 + threadIdx.x;   // 0..131071
    int seg = idx >> 15;
    int r = idx & 32767;
    float v;
    if      (seg == 0) v = Wq[(r & 63) * 512 + (r >> 6)];    // WqT[o][d] = Wq[d][o]
    else if (seg == 1) v = Wk[(r & 63) * 512 + (r >> 6)];
    else if (seg == 2) v = Wv[(r & 63) * 512 + (r >> 6)];
    else               v = Wp[(r & 511) * 64 + (r >> 9)];    // WpT[c][k] = Wp[k][c]
    ws[idx] = f2bf(v);
}

// ============================================================================
// Producer/consumer fused kernel — EXACT r16 chassis (103.4us best) + ONE
// change: consumer S-phase upgraded from 32xMFMA16+32xds_read_b64 to
// 16xMFMA32+16xds_read_b128 (identical S output layout: 16x16x32's D-mapping
// gives the same S[mt+c][n0+4g+r] per lane). Halves S instruction count, LDS
// ops, and dependent-chain depth. r17's three changes all REVERTED (epack-4bit
// added spill, sw128 widening was a no-op on conflicts, setprio starved the
// producers whose LDS writes gate everyone's barrier).
// Grid 256 (1 block/CU), 768 thr = 12 waves = 3/SIMD guaranteed (r13: blocks
// never co-schedule; r12: 1024-thr -> 64-reg cap spills; VGPR law 65536/thr).
//  - waves 0..7  consumers: 16 rows each; per head: 2 b128 Q reads, fused
//    max-free S(MFMA32)->exp->PV(MFMA16), oproj.
//  - waves 8..11 producers: K/V^T/Q of head h+1 (2 tiles of 16 rows).
// LDS 96 KB: 2 x {KB 8192, VTB 8192, QB 8192} ushorts. ONE barrier per head.
// DO NOT pass a >1 min-waves launch-bounds hint (r2/r5).
// ============================================================================
extern "C" __global__ __launch_bounds__(768, 1)
void geat_pc(const float* __restrict__ x, const int* __restrict__ edges,
             const float* __restrict__ bq, const float* __restrict__ bk,
             const float* __restrict__ bv, const float* __restrict__ ebias,
             const float* __restrict__ bp, const ushort_t* __restrict__ wt,
             float* __restrict__ out)
{
    __shared__ __align__(16) ushort_t sm[49152];  // 96 KB

    const int b    = blockIdx.x;
    const int tid  = threadIdx.x;
    const int w    = tid >> 6;          // wave 0..11
    const int lane = tid & 63;
    const int c    = lane & 15;
    const int g    = lane >> 4;
    const bool cons = (w < 8);
    const int mt   = cons ? (w * 16) : ((w - 8) * 32);   // consumer rows / producer base

    const ushort_t* WqT = wt;
    const ushort_t* WkT = wt + 32768;
    const ushort_t* WvT = wt + 65536;
    const ushort_t* WpT = wt + 98304;

    // ---- persistent per-role state ----
    unsigned epack[8];     // consumers: edge codes for row mt+c (n = 16nt+4g+r)
    bf16x8   pxA[2][2];    // producers: x frags for rows mt+16*tile+c
    if (cons) {
        const int* erow = edges + (size_t)b * NM * NM + (mt + c) * NM;
#pragma unroll
        for (int nt = 0; nt < 8; ++nt) {
            const int4 e4 = *(const int4*)&erow[nt * 16 + 4 * g];
            epack[nt] = (unsigned)(e4.x & 0xff) | ((unsigned)(e4.y & 0xff) << 8) |
                        ((unsigned)(e4.z & 0xff) << 16) | ((unsigned)(e4.w & 0xff) << 24);
        }
    } else {
#pragma unroll
        for (int tile = 0; tile < 2; ++tile) {
            const float* xb = x + (size_t)b * NM * ND + (mt + tile * 16 + c) * ND;
#pragma unroll
            for (int kt = 0; kt < 2; ++kt) {
                const float4 lo = *(const float4*)&xb[kt * 32 + 8 * g];
                const float4 hi = *(const float4*)&xb[kt * 32 + 8 * g + 4];
                bf16x8 f;
                f[0] = f2bf(lo.x); f[1] = f2bf(lo.y); f[2] = f2bf(lo.z); f[3] = f2bf(lo.w);
                f[4] = f2bf(hi.x); f[5] = f2bf(hi.y); f[6] = f2bf(hi.z); f[7] = f2bf(hi.w);
                pxA[tile][kt] = f;
            }
        }
    }

    f32x4 projacc[4];
#pragma unroll
    for (int i = 0; i < 4; ++i) projacc[i] = (f32x4)0.0f;

    // ---- producer: K + V^T + Q of head h2 into buf (32 rows: 2 tiles) ----
    auto PROJKVQ = [&](int h2, ushort_t* buf) {
        ushort_t* KBn = buf;
        ushort_t* VTn = buf + 8192;
        ushort_t* QBn = buf + 16384;
#pragma unroll
        for (int dt = 0; dt < 4; ++dt) {
            const int d0 = dt * 16;
            bf16x8 wqf[2], wkf[2], wvf[2];
#pragma unroll
            for (int kt = 0; kt < 2; ++kt) {
                const int woff = (h2 * 64 + d0 + c) * 64 + kt * 32 + 8 * g;
                wqf[kt] = *(const bf16x8*)&WqT[woff];
                wkf[kt] = *(const bf16x8*)&WkT[woff];
                wvf[kt] = *(const bf16x8*)&WvT[woff];
            }
            const float4 bqv = *(const float4*)&bq[h2 * 64 + d0 + 4 * g];
            const float4 bkv = *(const float4*)&bk[h2 * 64 + d0 + 4 * g];
            const float  bvv = bv[h2 * 64 + d0 + c];
#pragma unroll
            for (int tile = 0; tile < 2; ++tile) {
                f32x4 qT = (f32x4)0.0f, kT = (f32x4)0.0f, vn = (f32x4)0.0f;
#pragma unroll
                for (int kt = 0; kt < 2; ++kt) {
                    qT = MFMA(wqf[kt], pxA[tile][kt], qT);   // D: Q[row+c][d0+4g+r]
                    kT = MFMA(wkf[kt], pxA[tile][kt], kT);   // D: K[row+c][d0+4g+r]
                    vn = MFMA(pxA[tile][kt], wvf[kt], vn);   // D: V[row+4g+r][d0+c]
                }
                const int rowb = mt + tile * 16;
                uint2 qp, kp, vp;
                qp.x = pk2(qT[0] + bqv.x, qT[1] + bqv.y);
                qp.y = pk2(qT[2] + bqv.z, qT[3] + bqv.w);
                kp.x = pk2(kT[0] + bkv.x, kT[1] + bkv.y);
                kp.y = pk2(kT[2] + bkv.z, kT[3] + bkv.w);
                vp.x = pk2(vn[0] + bvv, vn[1] + bvv);
                vp.y = pk2(vn[2] + bvv, vn[3] + bvv);
                *(uint2*)&QBn[sw64(rowb + c, d0 + 4 * g)] = qp;
                *(uint2*)&KBn[sw64(rowb + c, d0 + 4 * g)] = kp;
                *(uint2*)&VTn[sw128(d0 + c, rowb + 4 * g)] = vp;
            }
        }
    };

    // ---- prologue: producers fill buffer 0 with head 0's K/V^T/Q ----
    if (!cons) PROJKVQ(0, sm);
    __syncthreads();

#pragma unroll 1
    for (int h = 0; h < NH; ++h) {
        ushort_t* bufc = sm + (h & 1) * 24576;
        ushort_t* bufn = sm + ((h & 1) ^ 1) * 24576;

        if (cons) {
            ushort_t* KBc = bufc;
            ushort_t* VTc = bufc + 8192;
            ushort_t* QBc = bufc + 16384;

            // ---- own-row Q granules as two b128 reads (k = kt*32 + 8g + j) ----
            bf16x8 qcur8[2];
#pragma unroll
            for (int kt = 0; kt < 2; ++kt)
                qcur8[kt] = *(const bf16x8*)&QBc[sw64(mt + c, kt * 32 + 8 * g)];

            const float eb0 = ebias[0 * NH + h], eb1 = ebias[1 * NH + h], eb2 = ebias[2 * NH + h];
            const float eb3 = ebias[3 * NH + h], eb4 = ebias[4 * NH + h];

            // ---- fused max-free S(MFMA32) -> exp -> PV(MFMA16), one n-tile at a time ----
            f32x4 ot[4];
#pragma unroll
            for (int dt = 0; dt < 4; ++dt) ot[dt] = (f32x4)0.0f;
            float sum = 0.f;
#pragma unroll
            for (int nt = 0; nt < 8; ++nt) {
                const int n0 = nt * 16;
                f32x4 acc = (f32x4)0.0f;
#pragma unroll
                for (int kt = 0; kt < 2; ++kt) {
                    const bf16x8 kgr = *(const bf16x8*)&KBc[sw64(n0 + c, kt * 32 + 8 * g)];
                    acc = MFMA(kgr, qcur8[kt], acc);   // D: S[mt+c][n0+4g+r] (same layout as MFMA16 pair)
                }
#pragma unroll
                for (int r = 0; r < 4; ++r) {
                    const int e = (epack[nt] >> (8 * r)) & 0xff;
                    const float bias = (e == 1) ? eb1 : (e == 2) ? eb2 : (e == 3) ? eb3 : (e == 4) ? eb4 : eb0;
                    float sv = acc[r] * 0.125f + bias;
                    sv = (sv > 0.f) ? sv : 0.2f * sv;          // leaky BEFORE mask (ref order)
                    acc[r] = (e > 0) ? __expf(sv) : 0.f;       // masked = exact 0, no exp
                }
                sum += (acc[0] + acc[1]) + (acc[2] + acc[3]);
                const bf16x4 pg = pk4(acc[0], acc[1], acc[2], acc[3]);   // unnormalized
#pragma unroll
                for (int dt = 0; dt < 4; ++dt) {
                    const bf16x4 vgr = *(const bf16x4*)&VTc[sw128(dt * 16 + c, n0 + 4 * g)];
                    ot[dt] = MFMA16(vgr, pg, ot[dt]);
                }
            }
            // row sum across the 4 lane-groups, then normalize O~ (16 muls)
            sum += __shfl_xor(sum, 16);
            sum += __shfl_xor(sum, 32);
            const float inv = 1.f / sum;

            // ---- out-proj accumulate from normalized O granules ----
            bf16x4 ogr[4];
#pragma unroll
            for (int dt = 0; dt < 4; ++dt)
                ogr[dt] = pk4(ot[dt][0] * inv, ot[dt][1] * inv, ot[dt][2] * inv, ot[dt][3] * inv);
#pragma unroll
            for (int nt4 = 0; nt4 < 4; ++nt4) {
                const int n0 = nt4 * 16;
#pragma unroll
                for (int dt = 0; dt < 4; ++dt) {
                    const bf16x4 wgr = *(const bf16x4*)&WpT[(n0 + c) * 512 + h * 64 + dt * 16 + 4 * g];
                    projacc[nt4] = MFMA16(ogr[dt], wgr, projacc[nt4]);
                }
            }
        } else if (h < NH - 1) {
            // ---- producers: next head's K/V^T/Q into the other buffer ----
            PROJKVQ(h + 1, bufn);
        }

        __syncthreads();   // one barrier per head (uniform flow: outside the role ifs)
    }

    // ---- epilogue: consumers add bp and store ----
    if (cons) {
        float* og = out + (size_t)b * NM * ND;
#pragma unroll
        for (int nt4 = 0; nt4 < 4; ++nt4) {
            const int n0 = nt4 * 16;
            const float bpv = bp[n0 + c];
#pragma unroll
            for (int r = 0; r < 4; ++r)
                og[(mt + 4 * g + r) * ND + n0 + c] = projacc[nt4][r] + bpv;
        }
    }
}

extern "C" void kernel_launch(void* const* d_in, const int* in_sizes, int n_in,
                              void* d_out, int out_size, void* d_ws, size_t ws_size,
                              hipStream_t stream) {
    const float* x     = (const float*)d_in[0];
    const int*   edges = (const int*)d_in[1];
    const float* Wq    = (const float*)d_in[2];
    const float* bq    = (const float*)d_in[3];
    const float* Wk    = (const float*)d_in[4];
    const float* bk    = (const float*)d_in[5];
    const float* Wv    = (const float*)d_in[6];
    const float* bv    = (const float*)d_in[7];
    const float* eb    = (const float*)d_in[8];
    const float* Wp    = (const float*)d_in[9];
    const float* bp    = (const float*)d_in[10];
    float* out = (float*)d_out;
    ushort_t* ws = (ushort_t*)d_ws;   // needs 262144 B

    hipLaunchKernelGGL(geat_prep, dim3(512), dim3(256), 0, stream, Wq, Wk, Wv, Wp, ws);
    hipLaunchKernelGGL(geat_pc, dim3(NB), dim3(768), 0, stream,
                       x, edges, bq, bk, bv, eb, bp, ws, out);
}

// Round 19
// 99.544 us; speedup vs baseline: 1.1353x; 1.0139x over previous
//
#include <hip/hip_runtime.h>

#define NB 256
#define NM 128
#define ND 64
#define NH 8

typedef float f32x4 __attribute__((ext_vector_type(4)));
typedef short bf16x8 __attribute__((ext_vector_type(8)));   // 8 bf16 = 4 VGPRs (16x16x32 A/B)
typedef short bf16x4 __attribute__((ext_vector_type(4)));   // 4 bf16 = 2 VGPRs (16x16x16 A/B)
typedef unsigned short ushort_t;

__device__ __forceinline__ ushort_t f2bf(float f) {   // RNE f32->bf16 (prep kernel only)
    unsigned int x = __float_as_uint(f);
    x += 0x7fffu + ((x >> 16) & 1u);
    return (ushort_t)(x >> 16);
}

// v_cvt_pk_bf16_f32: 2 f32 -> 2 bf16 (RNE) in ONE VALU op. No builtin on
// gfx950 (T12/m240) -> inline asm. Replaces the 4-op-per-element manual RNE
// (r18's pk2 = ~9 ops, pk4 = ~18 ops -> now 1 and 2).
__device__ __forceinline__ unsigned cvtpk(float lo, float hi) {
    unsigned r;
    asm("v_cvt_pk_bf16_f32 %0, %1, %2" : "=v"(r) : "v"(lo), "v"(hi));
    return r;
}
__device__ __forceinline__ unsigned pk2(float a, float b) { return cvtpk(a, b); }
__device__ __forceinline__ bf16x4 pk4(float a, float b, float c, float d) {
    union { unsigned u[2]; bf16x4 v; } t;
    t.u[0] = cvtpk(a, b);
    t.u[1] = cvtpk(c, d);
    return t.v;
}
__device__ __forceinline__ bf16x8 pk8(float4 lo, float4 hi) {
    union { unsigned u[4]; bf16x8 v; } t;
    t.u[0] = cvtpk(lo.x, lo.y);
    t.u[1] = cvtpk(lo.z, lo.w);
    t.u[2] = cvtpk(hi.x, hi.y);
    t.u[3] = cvtpk(hi.z, hi.w);
    return t.v;
}

// XOR-swizzled LDS indices (T2), write and read via the SAME helper.
// XOR by multiples of 8 elems permutes 8-element blocks: b64 (4-elem aligned)
// and b128 (8-elem aligned) accesses both stay contiguous+aligned under it.
__device__ __forceinline__ int sw64(int row, int col)  { return row * 64  + (col ^ ((row & 7) << 3)); }
__device__ __forceinline__ int sw128(int row, int col) { return row * 128 + (col ^ ((row & 7) << 3)); }

__device__ __forceinline__ f32x4 MFMA(bf16x8 a, bf16x8 b, f32x4 c) {
    return __builtin_amdgcn_mfma_f32_16x16x32_bf16(a, b, c, 0, 0, 0);
}

// 16x16x16 bf16 MFMA: A/B = 4 bf16/lane (lane(c,g): row/col=c, k=4g+j).
#if defined(__has_builtin)
#if __has_builtin(__builtin_amdgcn_mfma_f32_16x16x16bf16_1k)
#define HAVE_MFMA16 1
__device__ __forceinline__ f32x4 MFMA16(bf16x4 a, bf16x4 b, f32x4 c) {
    return __builtin_amdgcn_mfma_f32_16x16x16bf16_1k(a, b, c, 0, 0, 0);
}
#endif
#endif
#ifndef HAVE_MFMA16
__device__ __forceinline__ f32x4 MFMA16(bf16x4 a, bf16x4 b, f32x4 c) {
    f32x4 d;
    asm volatile("v_mfma_f32_16x16x16_bf16 %0, %1, %2, %3\n\ts_nop 7\n\ts_nop 7"
                 : "=v"(d) : "v"(a), "v"(b), "v"(c));
    return d;
}
#endif

// ---- prep: transpose weights to bf16 fragment layout in d_ws ----
// ws (ushort): WqT[512][64] @0, WkT @32768, WvT @65536, WpT[64][512] @98304 (256 KB)
extern "C" __global__ void geat_prep(const float* __restrict__ Wq,
                                     const float* __restrict__ Wk,
                                     const float* __restrict__ Wv,
                                     const float* __restrict__ Wp,
                                     ushort_t* __restrict__ ws)
{
    int idx = blockIdx.x * 256 + threadIdx.x;   // 0..131071
    int seg = idx >> 15;
    int r = idx & 32767;
    float v;
    if      (seg == 0) v = Wq[(r & 63) * 512 + (r >> 6)];    // WqT[o][d] = Wq[d][o]
    else if (seg == 1) v = Wk[(r & 63) * 512 + (r >> 6)];
    else if (seg == 2) v = Wv[(r & 63) * 512 + (r >> 6)];
    else               v = Wp[(r & 511) * 64 + (r >> 9)];    // WpT[c][k] = Wp[k][c]
    ws[idx] = f2bf(v);
}

// ============================================================================
// Producer/consumer fused kernel — EXACT r18 chassis (100.9us best) + ONE
// change: ALL bf16 packing via v_cvt_pk_bf16_f32 (1 op / 2 elems) instead of
// manual RNE bit math (4 ops/elem). Cuts the largest VALU consumer ~8x
// (VALUBusy was 31%, the biggest busy fraction).
// Grid 256 (1 block/CU), 768 thr = 12 waves = 3/SIMD guaranteed (r13: blocks
// never co-schedule; r12: 1024-thr -> 64-reg cap spills; VGPR law 65536/thr).
//  - waves 0..7  consumers: 16 rows each; per head: 2 b128 Q reads, fused
//    max-free S(MFMA32)->exp->PV(MFMA16), oproj. (r15: |s|<~6 so exp can't
//    overflow; masked = exact 0; normalize O~ once at the end.)
//  - waves 8..11 producers: K/V^T/Q of head h+1 (2 tiles of 16 rows).
// LDS 96 KB: 2 x {KB 8192, VTB 8192, QB 8192} ushorts. ONE barrier per head.
// DO NOT pass a >1 min-waves launch-bounds hint (r2/r5).
// ============================================================================
extern "C" __global__ __launch_bounds__(768, 1)
void geat_pc(const float* __restrict__ x, const int* __restrict__ edges,
             const float* __restrict__ bq, const float* __restrict__ bk,
             const float* __restrict__ bv, const float* __restrict__ ebias,
             const float* __restrict__ bp, const ushort_t* __restrict__ wt,
             float* __restrict__ out)
{
    __shared__ __align__(16) ushort_t sm[49152];  // 96 KB

    const int b    = blockIdx.x;
    const int tid  = threadIdx.x;
    const int w    = tid >> 6;          // wave 0..11
    const int lane = tid & 63;
    const int c    = lane & 15;
    const int g    = lane >> 4;
    const bool cons = (w < 8);
    const int mt   = cons ? (w * 16) : ((w - 8) * 32);   // consumer rows / producer base

    const ushort_t* WqT = wt;
    const ushort_t* WkT = wt + 32768;
    const ushort_t* WvT = wt + 65536;
    const ushort_t* WpT = wt + 98304;

    // ---- persistent per-role state ----
    unsigned epack[8];     // consumers: edge codes for row mt+c (n = 16nt+4g+r)
    bf16x8   pxA[2][2];    // producers: x frags for rows mt+16*tile+c
    if (cons) {
        const int* erow = edges + (size_t)b * NM * NM + (mt + c) * NM;
#pragma unroll
        for (int nt = 0; nt < 8; ++nt) {
            const int4 e4 = *(const int4*)&erow[nt * 16 + 4 * g];
            epack[nt] = (unsigned)(e4.x & 0xff) | ((unsigned)(e4.y & 0xff) << 8) |
                        ((unsigned)(e4.z & 0xff) << 16) | ((unsigned)(e4.w & 0xff) << 24);
        }
    } else {
#pragma unroll
        for (int tile = 0; tile < 2; ++tile) {
            const float* xb = x + (size_t)b * NM * ND + (mt + tile * 16 + c) * ND;
#pragma unroll
            for (int kt = 0; kt < 2; ++kt) {
                const float4 lo = *(const float4*)&xb[kt * 32 + 8 * g];
                const float4 hi = *(const float4*)&xb[kt * 32 + 8 * g + 4];
                pxA[tile][kt] = pk8(lo, hi);
            }
        }
    }

    f32x4 projacc[4];
#pragma unroll
    for (int i = 0; i < 4; ++i) projacc[i] = (f32x4)0.0f;

    // ---- producer: K + V^T + Q of head h2 into buf (32 rows: 2 tiles) ----
    auto PROJKVQ = [&](int h2, ushort_t* buf) {
        ushort_t* KBn = buf;
        ushort_t* VTn = buf + 8192;
        ushort_t* QBn = buf + 16384;
#pragma unroll
        for (int dt = 0; dt < 4; ++dt) {
            const int d0 = dt * 16;
            bf16x8 wqf[2], wkf[2], wvf[2];
#pragma unroll
            for (int kt = 0; kt < 2; ++kt) {
                const int woff = (h2 * 64 + d0 + c) * 64 + kt * 32 + 8 * g;
                wqf[kt] = *(const bf16x8*)&WqT[woff];
                wkf[kt] = *(const bf16x8*)&WkT[woff];
                wvf[kt] = *(const bf16x8*)&WvT[woff];
            }
            const float4 bqv = *(const float4*)&bq[h2 * 64 + d0 + 4 * g];
            const float4 bkv = *(const float4*)&bk[h2 * 64 + d0 + 4 * g];
            const float  bvv = bv[h2 * 64 + d0 + c];
#pragma unroll
            for (int tile = 0; tile < 2; ++tile) {
                f32x4 qT = (f32x4)0.0f, kT = (f32x4)0.0f, vn = (f32x4)0.0f;
#pragma unroll
                for (int kt = 0; kt < 2; ++kt) {
                    qT = MFMA(wqf[kt], pxA[tile][kt], qT);   // D: Q[row+c][d0+4g+r]
                    kT = MFMA(wkf[kt], pxA[tile][kt], kT);   // D: K[row+c][d0+4g+r]
                    vn = MFMA(pxA[tile][kt], wvf[kt], vn);   // D: V[row+4g+r][d0+c]
                }
                const int rowb = mt + tile * 16;
                uint2 qp, kp, vp;
                qp.x = pk2(qT[0] + bqv.x, qT[1] + bqv.y);
                qp.y = pk2(qT[2] + bqv.z, qT[3] + bqv.w);
                kp.x = pk2(kT[0] + bkv.x, kT[1] + bkv.y);
                kp.y = pk2(kT[2] + bkv.z, kT[3] + bkv.w);
                vp.x = pk2(vn[0] + bvv, vn[1] + bvv);
                vp.y = pk2(vn[2] + bvv, vn[3] + bvv);
                *(uint2*)&QBn[sw64(rowb + c, d0 + 4 * g)] = qp;
                *(uint2*)&KBn[sw64(rowb + c, d0 + 4 * g)] = kp;
                *(uint2*)&VTn[sw128(d0 + c, rowb + 4 * g)] = vp;
            }
        }
    };

    // ---- prologue: producers fill buffer 0 with head 0's K/V^T/Q ----
    if (!cons) PROJKVQ(0, sm);
    __syncthreads();

#pragma unroll 1
    for (int h = 0; h < NH; ++h) {
        ushort_t* bufc = sm + (h & 1) * 24576;
        ushort_t* bufn = sm + ((h & 1) ^ 1) * 24576;

        if (cons) {
            ushort_t* KBc = bufc;
            ushort_t* VTc = bufc + 8192;
            ushort_t* QBc = bufc + 16384;

            // ---- own-row Q granules as two b128 reads (k = kt*32 + 8g + j) ----
            bf16x8 qcur8[2];
#pragma unroll
            for (int kt = 0; kt < 2; ++kt)
                qcur8[kt] = *(const bf16x8*)&QBc[sw64(mt + c, kt * 32 + 8 * g)];

            const float eb0 = ebias[0 * NH + h], eb1 = ebias[1 * NH + h], eb2 = ebias[2 * NH + h];
            const float eb3 = ebias[3 * NH + h], eb4 = ebias[4 * NH + h];

            // ---- fused max-free S(MFMA32) -> exp -> PV(MFMA16), one n-tile at a time ----
            f32x4 ot[4];
#pragma unroll
            for (int dt = 0; dt < 4; ++dt) ot[dt] = (f32x4)0.0f;
            float sum = 0.f;
#pragma unroll
            for (int nt = 0; nt < 8; ++nt) {
                const int n0 = nt * 16;
                f32x4 acc = (f32x4)0.0f;
#pragma unroll
                for (int kt = 0; kt < 2; ++kt) {
                    const bf16x8 kgr = *(const bf16x8*)&KBc[sw64(n0 + c, kt * 32 + 8 * g)];
                    acc = MFMA(kgr, qcur8[kt], acc);   // D: S[mt+c][n0+4g+r]
                }
#pragma unroll
                for (int r = 0; r < 4; ++r) {
                    const int e = (epack[nt] >> (8 * r)) & 0xff;
                    const float bias = (e == 1) ? eb1 : (e == 2) ? eb2 : (e == 3) ? eb3 : (e == 4) ? eb4 : eb0;
                    float sv = acc[r] * 0.125f + bias;
                    sv = (sv > 0.f) ? sv : 0.2f * sv;          // leaky BEFORE mask (ref order)
                    acc[r] = (e > 0) ? __expf(sv) : 0.f;       // masked = exact 0, no exp
                }
                sum += (acc[0] + acc[1]) + (acc[2] + acc[3]);
                const bf16x4 pg = pk4(acc[0], acc[1], acc[2], acc[3]);   // unnormalized
#pragma unroll
                for (int dt = 0; dt < 4; ++dt) {
                    const bf16x4 vgr = *(const bf16x4*)&VTc[sw128(dt * 16 + c, n0 + 4 * g)];
                    ot[dt] = MFMA16(vgr, pg, ot[dt]);
                }
            }
            // row sum across the 4 lane-groups, then normalize O~ (16 muls)
            sum += __shfl_xor(sum, 16);
            sum += __shfl_xor(sum, 32);
            const float inv = 1.f / sum;

            // ---- out-proj accumulate from normalized O granules ----
            bf16x4 ogr[4];
#pragma unroll
            for (int dt = 0; dt < 4; ++dt)
                ogr[dt] = pk4(ot[dt][0] * inv, ot[dt][1] * inv, ot[dt][2] * inv, ot[dt][3] * inv);
#pragma unroll
            for (int nt4 = 0; nt4 < 4; ++nt4) {
                const int n0 = nt4 * 16;
#pragma unroll
                for (int dt = 0; dt < 4; ++dt) {
                    const bf16x4 wgr = *(const bf16x4*)&WpT[(n0 + c) * 512 + h * 64 + dt * 16 + 4 * g];
                    projacc[nt4] = MFMA16(ogr[dt], wgr, projacc[nt4]);
                }
            }
        } else if (h < NH - 1) {
            // ---- producers: next head's K/V^T/Q into the other buffer ----
            PROJKVQ(h + 1, bufn);
        }

        __syncthreads();   // one barrier per head (uniform flow: outside the role ifs)
    }

    // ---- epilogue: consumers add bp and store ----
    if (cons) {
        float* og = out + (size_t)b * NM * ND;
#pragma unroll
        for (int nt4 = 0; nt4 < 4; ++nt4) {
            const int n0 = nt4 * 16;
            const float bpv = bp[n0 + c];
#pragma unroll
            for (int r = 0; r < 4; ++r)
                og[(mt + 4 * g + r) * ND + n0 + c] = projacc[nt4][r] + bpv;
        }
    }
}

extern "C" void kernel_launch(void* const* d_in, const int* in_sizes, int n_in,
                              void* d_out, int out_size, void* d_ws, size_t ws_size,
                              hipStream_t stream) {
    const float* x     = (const float*)d_in[0];
    const int*   edges = (const int*)d_in[1];
    const float* Wq    = (const float*)d_in[2];
    const float* bq    = (const float*)d_in[3];
    const float* Wk    = (const float*)d_in[4];
    const float* bk    = (const float*)d_in[5];
    const float* Wv    = (const float*)d_in[6];
    const float* bv    = (const float*)d_in[7];
    const float* eb    = (const float*)d_in[8];
    const float* Wp    = (const float*)d_in[9];
    const float* bp    = (const float*)d_in[10];
    float* out = (float*)d_out;
    ushort_t* ws = (ushort_t*)d_ws;   // needs 262144 B

    hipLaunchKernelGGL(geat_prep, dim3(512), dim3(256), 0, stream, Wq, Wk, Wv, Wp, ws);
    hipLaunchKernelGGL(geat_pc, dim3(NB), dim3(768), 0, stream,
                       x, edges, bq, bk, bv, eb, bp, ws, out);
}